// Round 2
// baseline (122.879 us; speedup 1.0000x reference)
//
#include <hip/hip_runtime.h>

#define D_NODE 32
#define D_EDGE 16
#define D_IN   48
#define D_OUT  32
#define L2_EPS 1e-12f

#define NPB       128          // nodes per bucket
#define BKT_SHIFT 7            // log2(NPB)
#define MAX_NB    4096         // max buckets in fast path
#define CH        8192         // edges per chunk
#define CTH       1024         // threads for chunk kernels
#define EPT       (CH / CTH)   // edges per thread in chunk kernels
#define GR        128          // chunk rows per partial group
#define TILE      512          // edges per in-block CSR tile
#define ATH       512          // k_accum block size (4 lanes/node x 128 nodes)

// ===========================================================================
// Fast path: deterministic coarse bucket binning; NO f32 atomics anywhere.
// ===========================================================================

// K1: per-chunk LDS histogram of dst buckets -> counts2d[chunk][bucket]
__global__ __launch_bounds__(CTH) void k_chunkhist(
    const int* __restrict__ dst, int* __restrict__ counts2d, int n_edges, int nb)
{
    extern __shared__ int c[];
    for (int i = threadIdx.x; i < nb; i += CTH) c[i] = 0;
    __syncthreads();
    int base = blockIdx.x * CH + threadIdx.x;
    #pragma unroll
    for (int k = 0; k < EPT; ++k) {
        int i = base + k * CTH;
        if (i < n_edges) atomicAdd(&c[dst[i] >> BKT_SHIFT], 1);
    }
    __syncthreads();
    int* row = counts2d + (size_t)blockIdx.x * nb;
    for (int i = threadIdx.x; i < nb; i += CTH) row[i] = c[i];
}

// K2: partial column sums over groups of GR chunk rows (coalesced)
__global__ __launch_bounds__(256) void k_partial(
    const int* __restrict__ counts2d, int* __restrict__ partial, int nb, int nc)
{
    int b = blockIdx.x * 256 + threadIdx.x;
    if (b >= nb) return;
    int g = blockIdx.y;
    int c0 = g * GR, c1 = min(c0 + GR, nc);
    int s = 0;
    #pragma unroll 4
    for (int c = c0; c < c1; ++c) s += counts2d[(size_t)c * nb + b];
    partial[(size_t)g * nb + b] = s;
}

// K3: single block: bucket totals -> exclusive scan -> offsets; rewrite
// partial in place to column-exclusive prefixes (offsets folded in).
__global__ __launch_bounds__(1024) void k_offsets(
    int* __restrict__ partial, int* __restrict__ offsets, int nb, int ng)
{
    __shared__ int s[1024];
    const int PT = MAX_NB / 1024;
    int t = threadIdx.x;
    int tot[PT];
    int ts = 0;
    #pragma unroll
    for (int j = 0; j < PT; ++j) {
        int b = t * PT + j;
        int v = 0;
        if (b < nb) for (int g = 0; g < ng; ++g) v += partial[(size_t)g * nb + b];
        tot[j] = v; ts += v;
    }
    s[t] = ts;
    __syncthreads();
    for (int off = 1; off < 1024; off <<= 1) {
        int u = (t >= off) ? s[t - off] : 0;
        __syncthreads();
        s[t] += u;
        __syncthreads();
    }
    if (t == 1023) offsets[nb] = s[1023];
    int run = s[t] - ts;
    #pragma unroll
    for (int j = 0; j < PT; ++j) {
        int b = t * PT + j;
        if (b < nb) {
            offsets[b] = run;
            int r2 = run;
            for (int g = 0; g < ng; ++g) {
                int v = partial[(size_t)g * nb + b];
                partial[(size_t)g * nb + b] = r2;
                r2 += v;
            }
            run += tot[j];
        }
    }
}

// K4: rewrite counts2d in place to absolute slot bases (coalesced columns)
__global__ __launch_bounds__(256) void k_base2d(
    int* __restrict__ counts2d, const int* __restrict__ partial, int nb, int nc)
{
    int b = blockIdx.x * 256 + threadIdx.x;
    if (b >= nb) return;
    int g = blockIdx.y;
    int run = partial[(size_t)g * nb + b];
    int c0 = g * GR, c1 = min(c0 + GR, nc);
    #pragma unroll 4
    for (int c = c0; c < c1; ++c) {
        size_t idx = (size_t)c * nb + b;
        int v = counts2d[idx];
        counts2d[idx] = run;
        run += v;
    }
}

// K5: scatter edges into bucket-grouped slots: 8B meta2{src|dl<<20, eid}.
__global__ __launch_bounds__(CTH) void k_scatter(
    const int* __restrict__ dst, const int* __restrict__ src,
    const int* __restrict__ base2d, int2* __restrict__ meta2, int n_edges, int nb)
{
    extern __shared__ int sm[];
    int* lbase = sm;
    int* lrank = sm + nb;
    const int* brow = base2d + (size_t)blockIdx.x * nb;
    for (int i = threadIdx.x; i < nb; i += CTH) { lbase[i] = brow[i]; lrank[i] = 0; }
    __syncthreads();
    int base = blockIdx.x * CH + threadIdx.x;
    #pragma unroll
    for (int k = 0; k < EPT; ++k) {
        int i = base + k * CTH;
        if (i < n_edges) {
            int d = dst[i];
            int bkt = d >> BKT_SHIFT;
            int r = atomicAdd(&lrank[bkt], 1);
            int slot = lbase[bkt] + r;
            meta2[slot] = make_int2(src[i] | ((d & (NPB - 1)) << 20), i);
        }
    }
}

// K6: one 512-thread block per bucket (128 nodes, 4 lanes/node).
// Register-pipelined tiles: tile t+1's meta2 + e-row are gathered into 18
// VGPRs during tile t's scan/rank/WALK, so the two-level indirect gather
// latency never sits on the barrier-serialized critical path.
// Per tile (4 barriers):
//   P1: commit prefetched e-row regs -> pool4 (4 x ds_write_b128, uniform
//       banks) + hist from register mv; issue NEXT tile's meta2 load.
//   P2: wave0 scans cnt -> offs; threads 64..191 zero cnt2; all read myc.
//   P3: rank into csr; issue NEXT tile's e-row gather; zero cnt.
//   P4: WALK: 4 lanes/node; h row from global (L2/L3-hot), e row as one
//       ds_read_b128 from pool4 plane jg.
// NOTE: ntn is clamped to >=0 — guard is `threadIdx.x < ntn` with unsigned
// threadIdx.x; a negative int bound converts to a huge unsigned (OOB fault).
// pool4 aliased by mrow for the tail: mean -> affine -> l2norm.
__global__ __launch_bounds__(ATH) void k_accum(
    const float* __restrict__ h, const float4* __restrict__ e4,
    const float* __restrict__ W, const float* __restrict__ b,
    const int* __restrict__ offsets, const int2* __restrict__ meta2,
    float* __restrict__ out, int n_nodes)
{
    __shared__ float Ws[D_IN * D_OUT];
    __shared__ float bs[D_OUT];
    __shared__ int2 csr[TILE];
    __shared__ int cnt[NPB], cnt2[NPB], offs[NPB];
    __shared__ float4 pool4[4 * (TILE + 1)];   // 4 planes of [TILE+1] float4 (32.8KB)

    int b0 = offsets[blockIdx.x], b1 = offsets[blockIdx.x + 1];

    // prologue prefetch of tile 0 (meta2 + dependent e-row gather)
    int2 m2 = make_int2(0, 0);
    float4 v0 = make_float4(0.f, 0.f, 0.f, 0.f), v1 = v0, v2 = v0, v3 = v0;
    {
        int tn0 = min(TILE, b1 - b0);          // >= 0 (b1 >= b0 always)
        if ((int)threadIdx.x < tn0) {
            m2 = meta2[b0 + threadIdx.x];
            const float4* er = e4 + (size_t)m2.y * 4;
            v0 = er[0]; v1 = er[1]; v2 = er[2]; v3 = er[3];
        }
    }

    for (int i = threadIdx.x; i < D_IN * D_OUT; i += ATH) Ws[i] = W[i];
    if (threadIdx.x < D_OUT) bs[threadIdx.x] = b[threadIdx.x];
    if (threadIdx.x < NPB) { cnt[threadIdx.x] = 0; cnt2[threadIdx.x] = 0; }
    __syncthreads();

    int g  = threadIdx.x >> 2;     // node-local 0..127
    int jg = threadIdx.x & 3;      // dim-owner 0..3

    float4 ha0 = make_float4(0.f, 0.f, 0.f, 0.f);
    float4 ha1 = make_float4(0.f, 0.f, 0.f, 0.f);
    float4 ea  = make_float4(0.f, 0.f, 0.f, 0.f);
    float deg = 0.f;

    for (int t0 = b0; t0 < b1; t0 += TILE) {
        int tn  = min(TILE, b1 - t0);          // >= 1 inside loop
        int t1  = t0 + TILE;
        int ntn = (t1 < b1) ? min(TILE, b1 - t1) : 0;   // CLAMPED to >= 0
        int mv  = m2.x;
        int dl  = (mv >> 20) & (NPB - 1);

        // P1: issue next meta2 load first (in flight across B1+scan+B2),
        // then commit prefetched e-rows to LDS + hist from register.
        if ((int)threadIdx.x < ntn) m2 = meta2[t1 + threadIdx.x];
        if ((int)threadIdx.x < tn) {
            float4* pr = pool4 + threadIdx.x;
            pr[0]              = v0;
            pr[TILE + 1]       = v1;
            pr[2 * (TILE + 1)] = v2;
            pr[3 * (TILE + 1)] = v3;
            atomicAdd(&cnt[dl], 1);
        }
        __syncthreads();                       // B1: cnt + pool ready

        // P2: exclusive scan of 128 counts (wave 0); zero cnt2 concurrently
        if (threadIdx.x < 64) {
            int c0 = cnt[2 * threadIdx.x];
            int c1 = cnt[2 * threadIdx.x + 1];
            int p = c0 + c1;
            int x = p;
            #pragma unroll
            for (int o = 1; o < 64; o <<= 1) {
                int y = __shfl_up(x, o);
                if (threadIdx.x >= o) x += y;
            }
            int basex = x - p;
            offs[2 * threadIdx.x]     = basex;
            offs[2 * threadIdx.x + 1] = basex + c0;
        } else if (threadIdx.x < 64 + NPB) {
            cnt2[threadIdx.x - 64] = 0;
        }
        int myc = cnt[g];                      // cnt stable since B1
        __syncthreads();                       // B2: offs + cnt2 ready

        // P3: rank; issue next tile's e-row gather (drains under WALK);
        // zero cnt for the next tile's hist.
        int mybase = offs[g];
        if ((int)threadIdx.x < tn) {
            int r = atomicAdd(&cnt2[dl], 1);
            csr[offs[dl] + r] = make_int2(mv, threadIdx.x);
        }
        if ((int)threadIdx.x < ntn) {
            const float4* er = e4 + (size_t)m2.y * 4;
            v0 = er[0]; v1 = er[1]; v2 = er[2]; v3 = er[3];
        }
        if (threadIdx.x < NPB) cnt[threadIdx.x] = 0;
        deg += (float)myc;
        __syncthreads();                       // B3: csr ready

        // P4: WALK — h from global (hot), e as one ds_read_b128
        const float4* poolj = pool4 + jg * (TILE + 1);
        #pragma unroll 4
        for (int s = 0; s < myc; ++s) {
            int2 c = csr[mybase + s];          // ds_read_b64, broadcast in group
            const float4* hr = reinterpret_cast<const float4*>(
                h + (size_t)(c.x & 0xFFFFF) * D_NODE) + 2 * jg;
            float4 h0 = hr[0], h1 = hr[1];
            float4 ev = poolj[c.y];
            ha0.x += h0.x; ha0.y += h0.y; ha0.z += h0.z; ha0.w += h0.w;
            ha1.x += h1.x; ha1.y += h1.y; ha1.z += h1.z; ha1.w += h1.w;
            ea.x  += ev.x; ea.y  += ev.y; ea.z  += ev.z; ea.w  += ev.w;
        }
        __syncthreads();                       // B4: pool/csr/cnt reusable
    }

    // pool4 dead now: alias mrow over it (128*49*4B = 25.1KB <= 32.8KB)
    float (*mrow)[D_IN + 1] = reinterpret_cast<float (*)[D_IN + 1]>(pool4);
    __syncthreads();

    int node = blockIdx.x * NPB + g;
    if (node < n_nodes) {
        float inv = 1.f / (deg + 1.f);
        const float4* hs = reinterpret_cast<const float4*>(
            h + (size_t)node * D_NODE) + 2 * jg;
        float4 s0 = hs[0], s1 = hs[1];
        mrow[g][8 * jg + 0] = (ha0.x + s0.x) * inv;
        mrow[g][8 * jg + 1] = (ha0.y + s0.y) * inv;
        mrow[g][8 * jg + 2] = (ha0.z + s0.z) * inv;
        mrow[g][8 * jg + 3] = (ha0.w + s0.w) * inv;
        mrow[g][8 * jg + 4] = (ha1.x + s1.x) * inv;
        mrow[g][8 * jg + 5] = (ha1.y + s1.y) * inv;
        mrow[g][8 * jg + 6] = (ha1.z + s1.z) * inv;
        mrow[g][8 * jg + 7] = (ha1.w + s1.w) * inv;
        mrow[g][D_NODE + 4 * jg + 0] = ea.x * inv;
        mrow[g][D_NODE + 4 * jg + 1] = ea.y * inv;
        mrow[g][D_NODE + 4 * jg + 2] = ea.z * inv;
        mrow[g][D_NODE + 4 * jg + 3] = ea.w * inv;
    }
    __syncthreads();
    if (node >= n_nodes) return;

    // affine: lane jg computes outputs 8*jg .. 8*jg+7 (W broadcast from LDS)
    const float* row = mrow[g];
    float a[8];
    #pragma unroll
    for (int q = 0; q < 8; ++q) a[q] = bs[jg * 8 + q];
    #pragma unroll
    for (int k = 0; k < D_IN; ++k) {
        float mk = row[k];
        const float* w = Ws + k * D_OUT + jg * 8;
        #pragma unroll
        for (int q = 0; q < 8; ++q) a[q] += mk * w[q];
    }
    float sq = 0.f;
    #pragma unroll
    for (int q = 0; q < 8; ++q) sq += a[q] * a[q];
    sq += __shfl_xor(sq, 1);
    sq += __shfl_xor(sq, 2);
    float r = rsqrtf(fmaxf(sq, L2_EPS));
    float4* o4 = reinterpret_cast<float4*>(out + (size_t)node * D_OUT) + 2 * jg;
    o4[0] = make_float4(a[0] * r, a[1] * r, a[2] * r, a[3] * r);
    o4[1] = make_float4(a[4] * r, a[5] * r, a[6] * r, a[7] * r);
}

// ===========================================================================
// Fallback path (round-1, verified): global f32 atomics + per-node pass.
// ===========================================================================
__global__ __launch_bounds__(256) void scatter_kernel(
    const float* __restrict__ h, const float* __restrict__ e,
    const int* __restrict__ src, const int* __restrict__ dst,
    float* __restrict__ agg, float* __restrict__ deg, int n_edges)
{
    int tid  = blockIdx.x * blockDim.x + threadIdx.x;
    int edge = tid >> 4;
    int c    = tid & 15;
    if (edge >= n_edges) return;
    int s = src[edge], d = dst[edge];
    float v0 = h[(size_t)s * D_NODE + c];
    float v1 = h[(size_t)s * D_NODE + 16 + c];
    float v2 = e[(size_t)edge * D_EDGE + c];
    float* row = agg + (size_t)d * D_IN;
    atomicAdd(row + c, v0);
    atomicAdd(row + 16 + c, v1);
    atomicAdd(row + 32 + c, v2);
    if (c == 0) atomicAdd(deg + d, 1.0f);
}

__global__ __launch_bounds__(256) void node_kernel(
    const float* __restrict__ h, const float* __restrict__ W, const float* __restrict__ b,
    const float* __restrict__ agg, const float* __restrict__ deg,
    float* __restrict__ out, int n_nodes)
{
    __shared__ float Ws[D_IN * D_OUT];
    __shared__ float bs[D_OUT];
    for (int i = threadIdx.x; i < D_IN * D_OUT; i += blockDim.x) Ws[i] = W[i];
    if (threadIdx.x < D_OUT) bs[threadIdx.x] = b[threadIdx.x];
    __syncthreads();
    int node = blockIdx.x * blockDim.x + threadIdx.x;
    if (node >= n_nodes) return;
    const float4* h4 = reinterpret_cast<const float4*>(h + (size_t)node * D_NODE);
    const float4* a4 = reinterpret_cast<const float4*>(agg + (size_t)node * D_IN);
    float inv = 1.0f / (deg[node] + 1.0f);
    float m[D_IN];
    #pragma unroll
    for (int k = 0; k < D_NODE / 4; ++k) {
        float4 hv = h4[k]; float4 av = a4[k];
        m[4*k+0] = (hv.x + av.x) * inv; m[4*k+1] = (hv.y + av.y) * inv;
        m[4*k+2] = (hv.z + av.z) * inv; m[4*k+3] = (hv.w + av.w) * inv;
    }
    #pragma unroll
    for (int k = D_NODE / 4; k < D_IN / 4; ++k) {
        float4 av = a4[k];
        m[4*k+0] = av.x * inv; m[4*k+1] = av.y * inv;
        m[4*k+2] = av.z * inv; m[4*k+3] = av.w * inv;
    }
    float acc[D_OUT];
    #pragma unroll
    for (int j = 0; j < D_OUT; ++j) acc[j] = bs[j];
    #pragma unroll
    for (int k = 0; k < D_IN; ++k) {
        float mk = m[k];
        #pragma unroll
        for (int j = 0; j < D_OUT; ++j) acc[j] += mk * Ws[k * D_OUT + j];
    }
    float sq = 0.0f;
    #pragma unroll
    for (int j = 0; j < D_OUT; ++j) sq += acc[j] * acc[j];
    float r = rsqrtf(fmaxf(sq, L2_EPS));
    float4* o4 = reinterpret_cast<float4*>(out + (size_t)node * D_OUT);
    #pragma unroll
    for (int j = 0; j < D_OUT / 4; ++j) {
        float4 v;
        v.x = acc[4*j+0] * r; v.y = acc[4*j+1] * r;
        v.z = acc[4*j+2] * r; v.w = acc[4*j+3] * r;
        o4[j] = v;
    }
}

extern "C" void kernel_launch(void* const* d_in, const int* in_sizes, int n_in,
                              void* d_out, int out_size, void* d_ws, size_t ws_size,
                              hipStream_t stream) {
    const float* h   = (const float*)d_in[0];
    const float* e   = (const float*)d_in[1];
    const float* W   = (const float*)d_in[2];
    const float* b   = (const float*)d_in[3];
    const int*   src = (const int*)d_in[4];
    const int*   dst = (const int*)d_in[5];
    float* out = (float*)d_out;

    const int n_nodes = in_sizes[0] / D_NODE;
    const int n_edges = in_sizes[4];

    const int nb  = (n_nodes + NPB - 1) / NPB;
    const int nc  = (n_edges + CH - 1) / CH;
    const int ng  = (nc + GR - 1) / GR;
    const int nbt = (nb + 255) / 256;

    // ws layout (int units):
    //   counts2d[nc*nb] | partial[ng*nb] | offsets[nb+1] | pad8 | meta2 int2[E]
    size_t o_counts2d = 0;
    size_t o_partial  = o_counts2d + (size_t)nc * nb;
    size_t o_offsets  = o_partial + (size_t)ng * nb;
    size_t o_meta2    = (o_offsets + (size_t)nb + 1 + 1) & ~(size_t)1;
    size_t need       = (o_meta2 + (size_t)n_edges * 2) * sizeof(int);

    if (nb <= MAX_NB && n_nodes < (1 << 20) && need <= ws_size && n_edges > 0) {
        int* ws_i     = (int*)d_ws;
        int* counts2d = ws_i + o_counts2d;
        int* partial  = ws_i + o_partial;
        int* offsets  = ws_i + o_offsets;
        int2* meta2   = (int2*)(ws_i + o_meta2);

        dim3 g2(nbt, ng);
        k_chunkhist<<<nc, CTH, (size_t)nb * sizeof(int), stream>>>(
            dst, counts2d, n_edges, nb);
        k_partial<<<g2, 256, 0, stream>>>(counts2d, partial, nb, nc);
        k_offsets<<<1, 1024, 0, stream>>>(partial, offsets, nb, ng);
        k_base2d<<<g2, 256, 0, stream>>>(counts2d, partial, nb, nc);
        k_scatter<<<nc, CTH, (size_t)2 * nb * sizeof(int), stream>>>(
            dst, src, counts2d, meta2, n_edges, nb);
        k_accum<<<nb, ATH, 0, stream>>>(
            h, (const float4*)e, W, b, offsets, meta2, out, n_nodes);
    } else {
        float* agg = (float*)d_ws;
        float* deg = agg + (size_t)n_nodes * D_IN;
        hipMemsetAsync(d_ws, 0, (size_t)n_nodes * (D_IN + 1) * sizeof(float), stream);
        long long threads = (long long)n_edges * 16;
        scatter_kernel<<<(int)((threads + 255) / 256), 256, 0, stream>>>(h, e, src, dst, agg, deg, n_edges);
        node_kernel<<<(n_nodes + 255) / 256, 256, 0, stream>>>(h, W, b, agg, deg, out, n_nodes);
    }
}